// Round 5
// baseline (1047.035 us; speedup 1.0000x reference)
//
#include <hip/hip_runtime.h>
#include <hip/hip_bf16.h>
#include <string.h>

// Problem constants
#define B_ 64
#define T_ 256
#define F_ 64
#define U_ 512
#define G4_ 2048     // 4*U
#define KTOT 576     // F + U
#define KSTEPS 18    // KTOT/32

typedef __attribute__((ext_vector_type(8))) short short8;
typedef __attribute__((ext_vector_type(4))) float v4f;
typedef __attribute__((ext_vector_type(4))) int i4;
typedef unsigned short u16;

__device__ __forceinline__ float bf2f(u16 b) {
    unsigned int x = ((unsigned int)b) << 16;
    float f; memcpy(&f, &x, 4); return f;
}
__device__ __forceinline__ u16 f2bf(float f) {
    __hip_bfloat16 h = __float2bfloat16(f);
    u16 b; memcpy(&b, &h, 2); return b;
}
__device__ __forceinline__ float sigmoidf_(float x) { return 1.f / (1.f + __expf(-x)); }
__device__ __forceinline__ float tanhf_(float x) {   // clamped exp form (R8/R9-proven)
    float xc = fminf(15.f, fmaxf(-15.f, x));
    float e = __expf(2.f * xc);
    return (e - 1.f) / (e + 1.f);
}

// Dtype-flexible element load: fg=1 -> fp32, fg=0 -> bf16.
__device__ __forceinline__ float ldany(const void* p, size_t i, int fg) {
    return fg ? ((const float*)p)[i] : bf2f(((const u16*)p)[i]);
}

// Workspace layout (bytes; offsets 64-aligned) -- unchanged.
#define WS_FLAG   0             // int dtype-flag @0
#define WS_XB     64            // bf16 [T][B][F]          2,097,152
#define WS_WP     2097216       // bf16 packed weights     2,359,296
#define WS_H2     4456512       // bf16 [2][B][U]            131,072
#define WS_DOT    4718656       // fp32 [B][T]                65,536
#define WS_BIASF  4784192       // fp32 [4U]                   8,192
#define WS_ATTWF  4792384       // fp32 [T][T]               262,144
#define WS_ATTBF  5054528       // fp32 [T]                    1,024
#define WS_OUTWF  5055552       // fp32 [U]                    2,048
#define WS_OUTBF  5057600       // fp32 [1]                       64
#define WS_NEED   5057920

// ---------------------------------------------------------------------------
// Kernel 0: dtype detection (flag: 1 = fp32 inputs, 0 = bf16).
// ---------------------------------------------------------------------------
__global__ __launch_bounds__(256) void detect(const unsigned int* __restrict__ w,
                                              int* __restrict__ flag) {
    __shared__ int votes;
    if (threadIdx.x == 0) votes = 0;
    __syncthreads();
    unsigned int v = w[threadIdx.x];
    int e = (v >> 7) & 0xFF;
    if (e >= 100 && e <= 135) atomicAdd(&votes, 1);
    __syncthreads();
    if (threadIdx.x == 0) *flag = (votes < 200) ? 1 : 0;
}

// ---------------------------------------------------------------------------
// Kernel 1: canonicalize inputs.  x -> xb bf16 [T][B][F]; small arrays ->
// fp32; dot -> 0; h2 ping-pong -> 0 (tag bits (0,0) == tag 0, which is
// invalid under the period-3 tag scheme -> stale for every expected tag;
// zeros are also the correct h_{-1} at t=0 where the check is skipped).
// ---------------------------------------------------------------------------
__global__ __launch_bounds__(256) void convert(const void* __restrict__ x,
                                               const void* __restrict__ bias,
                                               const void* __restrict__ attW,
                                               const void* __restrict__ attb,
                                               const void* __restrict__ outW,
                                               const void* __restrict__ outb,
                                               const int* __restrict__ flag,
                                               u16* __restrict__ xb,
                                               float* __restrict__ biasf,
                                               float* __restrict__ attWf,
                                               float* __restrict__ attbf,
                                               float* __restrict__ outWf,
                                               float* __restrict__ outbf,
                                               float* __restrict__ dot,
                                               unsigned int* __restrict__ h2z) {
    int fg = *flag;
    size_t i = (size_t)blockIdx.x * 256 + threadIdx.x;
    if (i < 1048576) {
        float v = ldany(x, i, fg);
        int b = (int)(i >> 14), t = (int)((i >> 6) & 255), f = (int)(i & 63);
        xb[((size_t)t * B_ + b) * F_ + f] = f2bf(v);
        return;
    }
    i -= 1048576;
    if (i < 2048)  { biasf[i] = ldany(bias, i, fg); return; }
    i -= 2048;
    if (i < 65536) { attWf[i] = ldany(attW, i, fg); return; }
    i -= 65536;
    if (i < 256)   { attbf[i] = ldany(attb, i, fg); return; }
    i -= 256;
    if (i < 512)   { outWf[i] = ldany(outW, i, fg); return; }
    i -= 512;
    if (i < 1)     { outbf[i] = ldany(outb, i, fg); return; }
    i -= 1;
    if (i < 16384) { dot[i] = 0.f; return; }
    i -= 16384;
    if (i < 32768) { h2z[i] = 0u; return; }   // both h ping-pong buffers
}

// ---------------------------------------------------------------------------
// Kernel 2: pack [kernel; rec_kernel] into MFMA-B fragments, cols c'=4u+gate.
// Lane l of fragment (nt, ks) supplies B[k=ks*32+(l>>4)*8+j][col=nt*16+(l&15)].
// ---------------------------------------------------------------------------
__global__ __launch_bounds__(256) void pack_w(const void* __restrict__ kin,
                                              const void* __restrict__ krec,
                                              const int* __restrict__ flag,
                                              u16* __restrict__ Wp) {
    int fg = *flag;
    int gid = blockIdx.x * 256 + threadIdx.x;   // grid = 576*256 == 128*18*64
    int lane = gid & 63;
    int frag = gid >> 6;
    int nt = frag / KSTEPS;
    int ks = frag - nt * KSTEPS;
    int kbase = ks * 32 + (lane >> 4) * 8;
    int cp = nt * 16 + (lane & 15);
    int u = cp >> 2, gate = cp & 3;
    int C = gate * U_ + u;
    short8 v;
    for (int j = 0; j < 8; j++) {
        int k = kbase + j;
        float w = (k < F_) ? ldany(kin, (size_t)k * G4_ + C, fg)
                           : ldany(krec, (size_t)(k - F_) * G4_ + C, fg);
        v[j] = (short)f2bf(w);
    }
    *reinterpret_cast<short8*>(Wp + (size_t)gid * 8) = v;
}

// ---------------------------------------------------------------------------
// Kernel 3: PERSISTENT LSTM.  R16 = R15 (529us, one barrier/step, in-reg
// D-transpose) + SPECULATIVE EARLY POLL:
//
//  * Poll loads for step t+1 are ISSUED right after step t's h-store (they
//    fly during dp/loop-top/x-part); step t+1 starts with a WAIT-ONLY
//    vmcnt(0) + tag check.  Steady state: first sample already fresh ->
//    zero-retry acceptance; detect lag (~RT) is overlapped with the tail.
//    On a miss: fall back to the R10-proven fused load+vmcnt(0) loop.
//  * Tags upgraded 1-bit -> PERIOD-3 2-bit (tg = 1+(t mod 3), bit0 in the
//    lo-u16 LSB, bit1 in the hi-u16 LSB of each dword).  Every stale
//    source has tag != tg(t-1): prev-poll registers hold h_{t-2} (t-2 !=
//    t-1 mod 3), old buffer occupant is h_{t-3} (differs by 2 mod 3),
//    zero-init has tag 0 (never valid).  This closes R14's register-
//    staleness trap even against compiler-inserted copies.
//  * The wait asm takes q0/q1 as "+v" inouts (physical-reg tie: no
//    copy-before-landing hazard) + sched_barrier(0) per rule #18.
//  * Bias folded into MFMA acc-init (bias is per-column = per-lane const;
//    it travels with the value through the transpose) -- 4 fewer tail adds.
//  * Sleep removed for the first 8 retries (quantum 850 -> ~740 cyc).
// ---------------------------------------------------------------------------
__global__ __launch_bounds__(512, 1) void lstm_persist(const u16* __restrict__ xb,
                                                       const float* __restrict__ biasf,
                                                       const float* __restrict__ outWf,
                                                       const u16* __restrict__ Wp,
                                                       u16* __restrict__ h2,
                                                       float* __restrict__ dot) {
    __shared__ __align__(16) u16 stage[16 * 520];   // 16 rows x 512 h (+8 pad)
    __shared__ float dp[32][16][9];                 // dot partials: step x row x wave(+pad)

    int tid = threadIdx.x;
    int bid = blockIdx.x;
    int rg = bid & 3;                     // row-group: rows [16rg, 16rg+16)
    int gu = bid >> 2;                    // unit-group: units [32gu, 32gu+32)
    int w = tid >> 6, l = tid & 63;
    int nt = gu * 8 + w;                  // this wave's global n-tile

    // Weights into VGPRs: 18 fragments, loaded once.
    short8 W[KSTEPS];
    #pragma unroll
    for (int ks = 0; ks < KSTEPS; ks++)
        W[ks] = *reinterpret_cast<const short8*>(Wp + ((size_t)(nt * KSTEPS + ks) * 64 + l) * 8);

    // MFMA roles.
    int arow = rg * 16 + (l & 15);        // A row (global batch index)
    int koff = (l >> 4) * 8;              // k-chunk within a 32-wide ks
    // Poll/stage roles: wave w handles local rows 2w, 2w+1.
    int plr = 2 * w + (l >> 5);           // local row polled by this lane
    int pcol = (l & 31) * 16;             // u16 column of this lane's 32B chunk
    size_t poff = (size_t)(rg * 16 + plr) * U_ + pcol;   // offset into h buffer
    // Post-transpose elementwise roles: lane owns (row erow, unit 4nt+j).
    int e = l & 3;                        // row-within-quad after transpose
    int j = (l >> 2) & 3;                 // unit-within-wave
    int erow = 4 * (l >> 4) + e;          // local row 0..15
    int unit = 4 * nt + j;                // global unit
    // Per-lane column bias (col cp = nt*16 + (l&15); biasf is gate-major).
    int cp = nt * 16 + (l & 15);
    float bc = biasf[(cp & 3) * U_ + (cp >> 2)];
    float wout = outWf[unit];
    float c = 0.f;

    // Period-3 tag state: tg = tag stored with h_t; te = expected tag of
    // h_{t-1} (= previous step's tg).  tg cycles 1,2,3,1,...
    int tg = 1, te = 0;

    // Speculative early poll for t=0 (reads zero-init buffer; t=0 skips the
    // check so these are accepted as the correct h_{-1} zeros).
    i4 q0, q1;
    {
        const void* bp0 = (const void*)(h2 + (size_t)1 * (B_ * U_) + poff);
        asm volatile(
            "global_load_dwordx4 %0, %2, off sc0 sc1\n\t"
            "global_load_dwordx4 %1, %2, off offset:16 sc0 sc1"
            : "=v"(q0), "=v"(q1) : "v"(bp0) : "memory");
    }

    for (int t = 0; t < T_; t++) {
        u16* hcur = h2 + (size_t)(t & 1) * (B_ * U_);
        const u16* hprev = h2 + (size_t)((t + 1) & 1) * (B_ * U_);
        unsigned int pexp = (unsigned)(te & 1) | ((unsigned)((te >> 1) & 1) << 16);

        // x-part first: independent of h_{t-1}; overlaps the in-flight poll.
        // acc0 initialized with the per-column bias (same for all 4 D-rows).
        const u16* xrow = xb + ((size_t)t * B_ + arow) * F_;
        short8 a0 = *reinterpret_cast<const short8*>(xrow + koff);
        short8 a1 = *reinterpret_cast<const short8*>(xrow + 32 + koff);
        v4f acc0 = {bc, bc, bc, bc};
        v4f acc1 = {0.f, 0.f, 0.f, 0.f};
        acc0 = __builtin_amdgcn_mfma_f32_16x16x32_bf16(a0, W[0], acc0, 0, 0, 0);
        acc1 = __builtin_amdgcn_mfma_f32_16x16x32_bf16(a1, W[1], acc1, 0, 0, 0);

        // Wait-only on the early-issued poll loads ("+v" ties the pending
        // load destinations; sched_barrier fences the register reads).
        asm volatile("s_waitcnt vmcnt(0)" : "+v"(q0), "+v"(q1) :: "memory");
        __builtin_amdgcn_sched_barrier(0);

        if (t != 0) {
            unsigned bad = 0;
            bad |= (((unsigned)q0[0]) ^ pexp) & 0x00010001u;
            bad |= (((unsigned)q0[1]) ^ pexp) & 0x00010001u;
            bad |= (((unsigned)q0[2]) ^ pexp) & 0x00010001u;
            bad |= (((unsigned)q0[3]) ^ pexp) & 0x00010001u;
            bad |= (((unsigned)q1[0]) ^ pexp) & 0x00010001u;
            bad |= (((unsigned)q1[1]) ^ pexp) & 0x00010001u;
            bad |= (((unsigned)q1[2]) ^ pexp) & 0x00010001u;
            bad |= (((unsigned)q1[3]) ^ pexp) & 0x00010001u;
            if (__ballot(bad == 0) != ~0ull) {
                // Fallback: R10-proven fused load+drain retry loop.
                const void* bp = (const void*)(hprev + poff);
                int spins = 0;
                for (;;) {
                    asm volatile(
                        "global_load_dwordx4 %0, %2, off sc0 sc1\n\t"
                        "global_load_dwordx4 %1, %2, off offset:16 sc0 sc1\n\t"
                        "s_waitcnt vmcnt(0)"
                        : "=v"(q0), "=v"(q1) : "v"(bp) : "memory");
                    __builtin_amdgcn_sched_barrier(0);
                    bad  = (((unsigned)q0[0]) ^ pexp) & 0x00010001u;
                    bad |= (((unsigned)q0[1]) ^ pexp) & 0x00010001u;
                    bad |= (((unsigned)q0[2]) ^ pexp) & 0x00010001u;
                    bad |= (((unsigned)q0[3]) ^ pexp) & 0x00010001u;
                    bad |= (((unsigned)q1[0]) ^ pexp) & 0x00010001u;
                    bad |= (((unsigned)q1[1]) ^ pexp) & 0x00010001u;
                    bad |= (((unsigned)q1[2]) ^ pexp) & 0x00010001u;
                    bad |= (((unsigned)q1[3]) ^ pexp) & 0x00010001u;
                    if (__ballot(bad == 0) == ~0ull) break;
                    if (++spins > (1 << 14)) break;   // bailout: never hang
                    if (spins > 8) __builtin_amdgcn_s_sleep(1);
                }
            }
        }
        // Stage into LDS (row-major, 520-u16 stride).
        *reinterpret_cast<i4*>(&stage[plr * 520 + pcol])     = q0;
        *reinterpret_cast<i4*>(&stage[plr * 520 + pcol + 8]) = q1;
        __syncthreads();   // barrier 1: stage ready (only barrier per step)

        // h-part MFMAs from staged LDS.
        #pragma unroll
        for (int ks = 2; ks < KSTEPS; ks += 2) {
            short8 ah0 = *reinterpret_cast<const short8*>(
                &stage[(l & 15) * 520 + (ks - 2) * 32 + koff]);
            short8 ah1 = *reinterpret_cast<const short8*>(
                &stage[(l & 15) * 520 + (ks - 1) * 32 + koff]);
            acc0 = __builtin_amdgcn_mfma_f32_16x16x32_bf16(ah0, W[ks],     acc0, 0, 0, 0);
            acc1 = __builtin_amdgcn_mfma_f32_16x16x32_bf16(ah1, W[ks + 1], acc1, 0, 0, 0);
        }
        v4f acc = acc0 + acc1;

        // In-register 4x4 transpose among lane-quads (verified R15):
        // final(lane e, reg p) = orig(lane p, reg e).  Bias travels with
        // the value, so post-transpose g_p carries bias[gate p, unit].
        float g0 = acc[0], g1 = acc[1], g2 = acc[2], g3 = acc[3];
        {
            float t0 = __shfl_xor(g1, 1, 64);
            float t1 = __shfl_xor(g0, 1, 64);
            float t2 = __shfl_xor(g3, 1, 64);
            float t3 = __shfl_xor(g2, 1, 64);
            float b0 = ((0 ^ e) & 1) ? t0 : g0;
            float b1 = ((1 ^ e) & 1) ? t1 : g1;
            float b2 = ((2 ^ e) & 1) ? t2 : g2;
            float b3 = ((3 ^ e) & 1) ? t3 : g3;
            float u0 = __shfl_xor(b2, 2, 64);
            float u1 = __shfl_xor(b3, 2, 64);
            float u2 = __shfl_xor(b0, 2, 64);
            float u3 = __shfl_xor(b1, 2, 64);
            g0 = ((0 ^ e) & 2) ? u0 : b0;   // gate i of (row erow, unit), +bias
            g1 = ((1 ^ e) & 2) ? u1 : b1;   // gate f
            g2 = ((2 ^ e) & 2) ? u2 : b2;   // gate c
            g3 = ((3 ^ e) & 2) ? u3 : b3;   // gate o
        }

        // Elementwise: this lane owns (row erow, unit).  No LDS, no barrier.
        {
            float ig = sigmoidf_(g0);
            float fg = sigmoidf_(g1);
            float gc = tanhf_(g2);
            float og = sigmoidf_(g3);
            c = fg * c + ig * gc;
            float h = og * tanhf_(c);

            // Pack unit pair into a dword; period-3 2-bit tag: lo-u16 LSB =
            // tg bit0, hi-u16 LSB = tg bit1.  Even-j lane stores.
            float hp = __shfl_xor(h, 4, 64);   // partner unit+1 (lane bit2)
            if (((l >> 2) & 1) == 0) {
                unsigned int b0t = (unsigned)(tg & 1);
                unsigned int b1t = (unsigned)((tg >> 1) & 1);
                unsigned int pk = (unsigned int)(((unsigned)f2bf(h)  & 0xFFFEu) | b0t)
                                | ((unsigned int)(((unsigned)f2bf(hp) & 0xFFFEu) | b1t) << 16);
                void* sp = (void*)(hcur + (size_t)(rg * 16 + erow) * U_ + unit);
                asm volatile("global_store_dword %0, %1, off sc0 sc1"
                             :: "v"(sp), "v"(pk) : "memory");
            }

            // dot partial: sum this wave's 4 units (lane bits 2-3) per row.
            float s = h * wout;
            s += __shfl_xor(s, 4, 64);
            s += __shfl_xor(s, 8, 64);
            if ((l & 12) == 0) dp[t & 31][erow][w] = s;
        }

        // Flush dot partials every 32 steps (before the early poll issue so
        // the flush barrier's implicit drain doesn't eat the poll loads).
        if ((t & 31) == 31) {
            __syncthreads();
            int t0_ = t - 31;
            int tt = tid >> 4, row = tid & 15;
            float sum = 0.f;
            #pragma unroll
            for (int ww = 0; ww < 8; ww++) sum += dp[tt][row][ww];
            atomicAdd(&dot[(size_t)(rg * 16 + row) * T_ + (t0_ + tt)], sum);
        }

        // Speculative early poll for step t+1: hprev(t+1) == hcur(t).
        // Issued as late as possible (after dp flush) for max freshness.
        if (t < T_ - 1) {
            const void* bpn = (const void*)(hcur + poff);
            asm volatile(
                "global_load_dwordx4 %0, %2, off sc0 sc1\n\t"
                "global_load_dwordx4 %1, %2, off offset:16 sc0 sc1"
                : "=v"(q0), "=v"(q1) : "v"(bpn) : "memory");
        }

        // Rotate period-3 tags.
        te = tg;
        tg = (tg == 3) ? 1 : tg + 1;
    }
}

// ---------------------------------------------------------------------------
// Kernel 4: finale.  attention collapses to scalars:
//   coef_t = (t==0) ? 1 : sum_{j<t} att_W[t,j];  shift_t = (t==0) ? 0 : att_b[t]
//   out[b,t] = sigmoid(coef_t * dot[b,t] + shift_t * sum(out_W) + out_b)
// grid = 256 (one block per t).  Output dtype follows the input dtype flag.
// ---------------------------------------------------------------------------
__global__ __launch_bounds__(256) void finale(const float* __restrict__ attWf,
                                              const float* __restrict__ attbf,
                                              const float* __restrict__ outWf,
                                              const float* __restrict__ outbf,
                                              const float* __restrict__ dot,
                                              const int* __restrict__ flag,
                                              void* __restrict__ out) {
    __shared__ float red[256];
    int t = blockIdx.x, tid = threadIdx.x;
    int fg = *flag;

    float v = (tid < t) ? attWf[(size_t)t * T_ + tid] : 0.f;
    red[tid] = v; __syncthreads();
    for (int s = 128; s > 0; s >>= 1) { if (tid < s) red[tid] += red[tid + s]; __syncthreads(); }
    float coef = (t == 0) ? 1.f : red[0];
    __syncthreads();
    red[tid] = outWf[tid] + outWf[tid + 256]; __syncthreads();
    for (int s = 128; s > 0; s >>= 1) { if (tid < s) red[tid] += red[tid + s]; __syncthreads(); }
    float sumW = red[0];

    float base = ((t == 0) ? 0.f : attbf[t]) * sumW + outbf[0];

    if (tid < B_) {
        float s = sigmoidf_(coef * dot[(size_t)tid * T_ + t] + base);
        size_t idx = (size_t)tid * T_ + t;
        if (fg) ((float*)out)[idx] = s;
        else    ((u16*)out)[idx] = f2bf(s);
    }
}

// ---------------------------------------------------------------------------
extern "C" void kernel_launch(void* const* d_in, const int* in_sizes, int n_in,
                              void* d_out, int out_size, void* d_ws, size_t ws_size,
                              hipStream_t stream) {
    const void* x    = d_in[0];
    const void* kin  = d_in[1];
    const void* krec = d_in[2];
    const void* bias = d_in[3];
    const void* attW = d_in[4];
    const void* attb = d_in[5];
    const void* outW = d_in[6];
    const void* outb = d_in[7];

    if (ws_size < (size_t)WS_NEED) return;

    char* ws = (char*)d_ws;
    int*   flag  = (int*)(ws + WS_FLAG);
    u16*   xb    = (u16*)(ws + WS_XB);
    u16*   Wp    = (u16*)(ws + WS_WP);
    u16*   h2    = (u16*)(ws + WS_H2);
    float* dot   = (float*)(ws + WS_DOT);
    float* biasf = (float*)(ws + WS_BIASF);
    float* attWf = (float*)(ws + WS_ATTWF);
    float* attbf = (float*)(ws + WS_ATTBF);
    float* outWf = (float*)(ws + WS_OUTWF);
    float* outbf = (float*)(ws + WS_OUTBF);

    detect<<<1, 256, 0, stream>>>((const unsigned int*)kin, flag);
    convert<<<4556, 256, 0, stream>>>(x, bias, attW, attb, outW, outb, flag,
                                      xb, biasf, attWf, attbf, outWf, outbf, dot,
                                      (unsigned int*)h2);
    pack_w<<<576, 256, 0, stream>>>(kin, krec, flag, Wp);
    lstm_persist<<<64, 512, 0, stream>>>(xb, biasf, outWf, Wp, h2, dot);
    finale<<<256, 256, 0, stream>>>(attWf, attbf, outWf, outbf, dot, flag, d_out);
}

// Round 7
// 610.991 us; speedup vs baseline: 1.7137x; 1.7137x over previous
//
#include <hip/hip_runtime.h>
#include <hip/hip_bf16.h>
#include <string.h>

// Problem constants
#define B_ 64
#define T_ 256
#define F_ 64
#define U_ 512
#define G4_ 2048     // 4*U
#define KTOT 576     // F + U
#define KSTEPS 18    // KTOT/32

typedef __attribute__((ext_vector_type(8))) short short8;
typedef __attribute__((ext_vector_type(4))) float v4f;
typedef __attribute__((ext_vector_type(4))) int i4;
typedef unsigned short u16;

__device__ __forceinline__ float bf2f(u16 b) {
    unsigned int x = ((unsigned int)b) << 16;
    float f; memcpy(&f, &x, 4); return f;
}
__device__ __forceinline__ u16 f2bf(float f) {
    __hip_bfloat16 h = __float2bfloat16(f);
    u16 b; memcpy(&b, &h, 2); return b;
}
__device__ __forceinline__ float sigmoidf_(float x) { return 1.f / (1.f + __expf(-x)); }
__device__ __forceinline__ float tanhf_(float x) {   // clamped exp form (R8/R9-proven)
    float xc = fminf(15.f, fmaxf(-15.f, x));
    float e = __expf(2.f * xc);
    return (e - 1.f) / (e + 1.f);
}

// Dtype-flexible element load: fg=1 -> fp32, fg=0 -> bf16.
__device__ __forceinline__ float ldany(const void* p, size_t i, int fg) {
    return fg ? ((const float*)p)[i] : bf2f(((const u16*)p)[i]);
}

// Workspace layout (bytes; offsets 64-aligned) -- unchanged.
#define WS_FLAG   0             // int dtype-flag @0
#define WS_XB     64            // bf16 [T][B][F]          2,097,152
#define WS_WP     2097216       // bf16 packed weights     2,359,296
#define WS_H2     4456512       // bf16 [2][B][U]            131,072
#define WS_DOT    4718656       // fp32 [B][T]                65,536
#define WS_BIASF  4784192       // fp32 [4U]                   8,192
#define WS_ATTWF  4792384       // fp32 [T][T]               262,144
#define WS_ATTBF  5054528       // fp32 [T]                    1,024
#define WS_OUTWF  5055552       // fp32 [U]                    2,048
#define WS_OUTBF  5057600       // fp32 [1]                       64
#define WS_NEED   5057920

// ---------------------------------------------------------------------------
// Kernel 0: dtype detection (flag: 1 = fp32 inputs, 0 = bf16).
// ---------------------------------------------------------------------------
__global__ __launch_bounds__(256) void detect(const unsigned int* __restrict__ w,
                                              int* __restrict__ flag) {
    __shared__ int votes;
    if (threadIdx.x == 0) votes = 0;
    __syncthreads();
    unsigned int v = w[threadIdx.x];
    int e = (v >> 7) & 0xFF;
    if (e >= 100 && e <= 135) atomicAdd(&votes, 1);
    __syncthreads();
    if (threadIdx.x == 0) *flag = (votes < 200) ? 1 : 0;
}

// ---------------------------------------------------------------------------
// Kernel 1: canonicalize inputs.  x -> xb bf16 [T][B][F]; small arrays ->
// fp32; dot -> 0; h2 ping-pong -> 0 (tag 0 == stale for every expected tag;
// zeros are also the correct h_{-1} at t=0 where the check is skipped).
// ---------------------------------------------------------------------------
__global__ __launch_bounds__(256) void convert(const void* __restrict__ x,
                                               const void* __restrict__ bias,
                                               const void* __restrict__ attW,
                                               const void* __restrict__ attb,
                                               const void* __restrict__ outW,
                                               const void* __restrict__ outb,
                                               const int* __restrict__ flag,
                                               u16* __restrict__ xb,
                                               float* __restrict__ biasf,
                                               float* __restrict__ attWf,
                                               float* __restrict__ attbf,
                                               float* __restrict__ outWf,
                                               float* __restrict__ outbf,
                                               float* __restrict__ dot,
                                               unsigned int* __restrict__ h2z) {
    int fg = *flag;
    size_t i = (size_t)blockIdx.x * 256 + threadIdx.x;
    if (i < 1048576) {
        float v = ldany(x, i, fg);
        int b = (int)(i >> 14), t = (int)((i >> 6) & 255), f = (int)(i & 63);
        xb[((size_t)t * B_ + b) * F_ + f] = f2bf(v);
        return;
    }
    i -= 1048576;
    if (i < 2048)  { biasf[i] = ldany(bias, i, fg); return; }
    i -= 2048;
    if (i < 65536) { attWf[i] = ldany(attW, i, fg); return; }
    i -= 65536;
    if (i < 256)   { attbf[i] = ldany(attb, i, fg); return; }
    i -= 256;
    if (i < 512)   { outWf[i] = ldany(outW, i, fg); return; }
    i -= 512;
    if (i < 1)     { outbf[i] = ldany(outb, i, fg); return; }
    i -= 1;
    if (i < 16384) { dot[i] = 0.f; return; }
    i -= 16384;
    if (i < 32768) { h2z[i] = 0u; return; }   // both h ping-pong buffers
}

// ---------------------------------------------------------------------------
// Kernel 2: pack [kernel; rec_kernel] into MFMA-B fragments, cols c'=4u+gate.
// Lane l of fragment (nt, ks) supplies B[k=ks*32+(l>>4)*8+j][col=nt*16+(l&15)].
// ---------------------------------------------------------------------------
__global__ __launch_bounds__(256) void pack_w(const void* __restrict__ kin,
                                              const void* __restrict__ krec,
                                              const int* __restrict__ flag,
                                              u16* __restrict__ Wp) {
    int fg = *flag;
    int gid = blockIdx.x * 256 + threadIdx.x;   // grid = 576*256 == 128*18*64
    int lane = gid & 63;
    int frag = gid >> 6;
    int nt = frag / KSTEPS;
    int ks = frag - nt * KSTEPS;
    int kbase = ks * 32 + (lane >> 4) * 8;
    int cp = nt * 16 + (lane & 15);
    int u = cp >> 2, gate = cp & 3;
    int C = gate * U_ + u;
    short8 v;
    for (int j = 0; j < 8; j++) {
        int k = kbase + j;
        float w = (k < F_) ? ldany(kin, (size_t)k * G4_ + C, fg)
                           : ldany(krec, (size_t)(k - F_) * G4_ + C, fg);
        v[j] = (short)f2bf(w);
    }
    *reinterpret_cast<short8*>(Wp + (size_t)gid * 8) = v;
}

// ---------------------------------------------------------------------------
// Kernel 3: PERSISTENT LSTM.  R18 = R17 with the s_sleep constant-arg fix
// (builtin requires a literal; branch split into two constant calls).
// R17 rationale, unchanged: R15 (529us proven: one barrier/step, in-reg
// D-transpose, R10 poll) + three POLL-INVARIANT shaves.  R16's speculative
// early poll stays REVERTED (its end-of-step sample raced the other 15
// producers and its sleepless retries congested IF: 529->980us).
//
//  (1) Bias folded into MFMA acc-init (R16-validated independently): the
//      per-column bias rides through the lane transpose; 4 fewer tail adds.
//  (2) FOUR accumulator chains (A: ks 0,4,8,12,16 / B: 1,5,9,13,17 /
//      C: 2,6,10,14 / D: 3,7,11,15): serial MFMA depth ~9 -> ~5 on the
//      poll-accept -> h-store critical path.
//  (3) Graduated backoff: retries 1-3 sleepless (RT-paced), then sleep(1),
//      sleep(2) past 16.  Bounded extra traffic, smaller detect quantum.
// ---------------------------------------------------------------------------
__global__ __launch_bounds__(512, 1) void lstm_persist(const u16* __restrict__ xb,
                                                       const float* __restrict__ biasf,
                                                       const float* __restrict__ outWf,
                                                       const u16* __restrict__ Wp,
                                                       u16* __restrict__ h2,
                                                       float* __restrict__ dot) {
    __shared__ __align__(16) u16 stage[16 * 520];   // 16 rows x 512 h (+8 pad)
    __shared__ float dp[32][16][9];                 // dot partials: step x row x wave(+pad)

    int tid = threadIdx.x;
    int bid = blockIdx.x;
    int rg = bid & 3;                     // row-group: rows [16rg, 16rg+16)
    int gu = bid >> 2;                    // unit-group: units [32gu, 32gu+32)
    int w = tid >> 6, l = tid & 63;
    int nt = gu * 8 + w;                  // this wave's global n-tile

    // Weights into VGPRs: 18 fragments, loaded once.
    short8 W[KSTEPS];
    #pragma unroll
    for (int ks = 0; ks < KSTEPS; ks++)
        W[ks] = *reinterpret_cast<const short8*>(Wp + ((size_t)(nt * KSTEPS + ks) * 64 + l) * 8);

    // MFMA roles.
    int arow = rg * 16 + (l & 15);        // A row (global batch index)
    int koff = (l >> 4) * 8;              // k-chunk within a 32-wide ks
    // Poll/stage roles: wave w handles local rows 2w, 2w+1.
    int plr = 2 * w + (l >> 5);           // local row polled by this lane
    int pcol = (l & 31) * 16;             // u16 column of this lane's 32B chunk
    // Post-transpose elementwise roles: lane owns (row erow, unit 4nt+j).
    int e = l & 3;                        // row-within-quad after transpose
    int erow = 4 * (l >> 4) + e;          // local row 0..15
    int unit = 4 * nt + ((l >> 2) & 3);   // global unit
    // Per-lane column bias (col cp = nt*16 + (l&15); biasf is gate-major).
    int cp = nt * 16 + (l & 15);
    float bc = biasf[(cp & 3) * U_ + (cp >> 2)];
    float wout = outWf[unit];
    float c = 0.f;

    for (int t = 0; t < T_; t++) {
        u16* hcur = h2 + (size_t)(t & 1) * (B_ * U_);
        const u16* hprev = h2 + (size_t)((t + 1) & 1) * (B_ * U_);
        unsigned int wtag = ((unsigned)(t >> 1) & 1u) ^ 1u;
        unsigned int rpat = ((((unsigned)(t - 1) >> 1) & 1u) ^ 1u) * 0x00010001u;

        // x-part first: independent of h_{t-1}; runs before the poll so the
        // poll-success -> h-store path holds only h-MFMAs + elementwise.
        // accA initialized with the per-column bias (same for all 4 D-rows).
        const u16* xrow = xb + ((size_t)t * B_ + arow) * F_;
        short8 a0 = *reinterpret_cast<const short8*>(xrow + koff);
        short8 a1 = *reinterpret_cast<const short8*>(xrow + 32 + koff);
        v4f accA = {bc, bc, bc, bc};
        v4f accB = {0.f, 0.f, 0.f, 0.f};
        v4f accC = {0.f, 0.f, 0.f, 0.f};
        v4f accD = {0.f, 0.f, 0.f, 0.f};
        accA = __builtin_amdgcn_mfma_f32_16x16x32_bf16(a0, W[0], accA, 0, 0, 0);
        accB = __builtin_amdgcn_mfma_f32_16x16x32_bf16(a1, W[1], accB, 0, 0, 0);
        __builtin_amdgcn_sched_barrier(0);   // pin x-MFMAs before the poll

        // Poll this wave's 2 rows of h_{t-1}: 2 coherent 16B loads per lane,
        // loads + vmcnt(0) fused in ONE asm block (the only safe primitive:
        // registers are always landed when checked).  Accept when all 8
        // dwords are fresh wave-unanimously.  R10-proven protocol; only the
        // backoff schedule differs (graduated: 3 sleepless, sleep(1), (2)).
        i4 q0, q1;
        {
            const void* bp = (const void*)(hprev + (size_t)(rg * 16 + plr) * U_ + pcol);
            int spins = 0;
            for (;;) {
                asm volatile(
                    "global_load_dwordx4 %0, %2, off sc0 sc1\n\t"
                    "global_load_dwordx4 %1, %2, off offset:16 sc0 sc1\n\t"
                    "s_waitcnt vmcnt(0)"
                    : "=v"(q0), "=v"(q1) : "v"(bp) : "memory");
                if (t == 0) break;        // zeros are the correct h_{-1}
                unsigned bad = 0;
                bad |= (((unsigned)q0[0]) ^ rpat) & 0x00010001u;
                bad |= (((unsigned)q0[1]) ^ rpat) & 0x00010001u;
                bad |= (((unsigned)q0[2]) ^ rpat) & 0x00010001u;
                bad |= (((unsigned)q0[3]) ^ rpat) & 0x00010001u;
                bad |= (((unsigned)q1[0]) ^ rpat) & 0x00010001u;
                bad |= (((unsigned)q1[1]) ^ rpat) & 0x00010001u;
                bad |= (((unsigned)q1[2]) ^ rpat) & 0x00010001u;
                bad |= (((unsigned)q1[3]) ^ rpat) & 0x00010001u;
                if (__ballot(bad == 0) == ~0ull) break;
                if (++spins > (1 << 14)) break;   // bailout: never hang
                if (spins > 16)     __builtin_amdgcn_s_sleep(2);
                else if (spins > 3) __builtin_amdgcn_s_sleep(1);
            }
        }
        // Stage into LDS (row-major, 520-u16 stride).
        *reinterpret_cast<i4*>(&stage[plr * 520 + pcol])     = q0;
        *reinterpret_cast<i4*>(&stage[plr * 520 + pcol + 8]) = q1;
        __syncthreads();   // barrier 1: stage ready (only barrier per step)

        // h-part MFMAs from staged LDS, round-robined over 4 chains.
        // W[m] consumes h-chunk (m-2)*32, m = 2..17.
        #pragma unroll
        for (int m = 2; m < KSTEPS; m += 4) {
            const u16* srow = &stage[(l & 15) * 520 + koff];
            short8 h0 = *reinterpret_cast<const short8*>(srow + (m - 2) * 32);
            short8 h1 = *reinterpret_cast<const short8*>(srow + (m - 1) * 32);
            short8 h2v = *reinterpret_cast<const short8*>(srow + (m    ) * 32);
            short8 h3 = *reinterpret_cast<const short8*>(srow + (m + 1) * 32);
            accC = __builtin_amdgcn_mfma_f32_16x16x32_bf16(h0, W[m],     accC, 0, 0, 0);
            accD = __builtin_amdgcn_mfma_f32_16x16x32_bf16(h1, W[m + 1], accD, 0, 0, 0);
            accA = __builtin_amdgcn_mfma_f32_16x16x32_bf16(h2v, W[m + 2], accA, 0, 0, 0);
            accB = __builtin_amdgcn_mfma_f32_16x16x32_bf16(h3, W[m + 3], accB, 0, 0, 0);
        }
        v4f acc = (accA + accC) + (accB + accD);

        // In-register 4x4 transpose among lane-quads (verified R15):
        // final(lane e, reg p) = orig(lane p, reg e).  Bias travels with
        // the value, so post-transpose g_p carries bias[gate p, unit].
        float g0 = acc[0], g1 = acc[1], g2 = acc[2], g3 = acc[3];
        {
            float t0 = __shfl_xor(g1, 1, 64);
            float t1 = __shfl_xor(g0, 1, 64);
            float t2 = __shfl_xor(g3, 1, 64);
            float t3 = __shfl_xor(g2, 1, 64);
            float b0 = ((0 ^ e) & 1) ? t0 : g0;
            float b1 = ((1 ^ e) & 1) ? t1 : g1;
            float b2 = ((2 ^ e) & 1) ? t2 : g2;
            float b3 = ((3 ^ e) & 1) ? t3 : g3;
            float u0 = __shfl_xor(b2, 2, 64);
            float u1 = __shfl_xor(b3, 2, 64);
            float u2 = __shfl_xor(b0, 2, 64);
            float u3 = __shfl_xor(b1, 2, 64);
            g0 = ((0 ^ e) & 2) ? u0 : b0;   // gate i of (row erow, unit), +bias
            g1 = ((1 ^ e) & 2) ? u1 : b1;   // gate f
            g2 = ((2 ^ e) & 2) ? u2 : b2;   // gate c
            g3 = ((3 ^ e) & 2) ? u3 : b3;   // gate o
        }

        // Elementwise: this lane owns (row erow, unit).  No LDS, no barrier.
        {
            float ig = sigmoidf_(g0);
            float fg = sigmoidf_(g1);
            float gc = tanhf_(g2);
            float og = sigmoidf_(g3);
            c = fg * c + ig * gc;
            float h = og * tanhf_(c);

            // Pack unit pair into a dword with LSB tags; even-j lane stores.
            float hp = __shfl_xor(h, 4, 64);   // partner unit+1 (lane bit2)
            if (((l >> 2) & 1) == 0) {
                unsigned int pk = (unsigned int)(((unsigned)f2bf(h)  & 0xFFFEu) | wtag)
                                | ((unsigned int)(((unsigned)f2bf(hp) & 0xFFFEu) | wtag) << 16);
                void* sp = (void*)(hcur + (size_t)(rg * 16 + erow) * U_ + unit);
                asm volatile("global_store_dword %0, %1, off sc0 sc1"
                             :: "v"(sp), "v"(pk) : "memory");
            }

            // dot partial: sum this wave's 4 units (lane bits 2-3) per row.
            float s = h * wout;
            s += __shfl_xor(s, 4, 64);
            s += __shfl_xor(s, 8, 64);
            if ((l & 12) == 0) dp[t & 31][erow][w] = s;
        }

        // Flush dot partials every 32 steps: 512 threads cover 32x16 slots,
        // summing the 8 per-wave partials.  barrier 1 of step t+1 keeps any
        // fast wave from overwriting dp slot 0 before these reads finish.
        if ((t & 31) == 31) {
            __syncthreads();
            int t0_ = t - 31;
            int tt = tid >> 4, row = tid & 15;
            float sum = 0.f;
            #pragma unroll
            for (int ww = 0; ww < 8; ww++) sum += dp[tt][row][ww];
            atomicAdd(&dot[(size_t)(rg * 16 + row) * T_ + (t0_ + tt)], sum);
        }
    }
}

// ---------------------------------------------------------------------------
// Kernel 4: finale.  attention collapses to scalars:
//   coef_t = (t==0) ? 1 : sum_{j<t} att_W[t,j];  shift_t = (t==0) ? 0 : att_b[t]
//   out[b,t] = sigmoid(coef_t * dot[b,t] + shift_t * sum(out_W) + out_b)
// grid = 256 (one block per t).  Output dtype follows the input dtype flag.
// ---------------------------------------------------------------------------
__global__ __launch_bounds__(256) void finale(const float* __restrict__ attWf,
                                              const float* __restrict__ attbf,
                                              const float* __restrict__ outWf,
                                              const float* __restrict__ outbf,
                                              const float* __restrict__ dot,
                                              const int* __restrict__ flag,
                                              void* __restrict__ out) {
    __shared__ float red[256];
    int t = blockIdx.x, tid = threadIdx.x;
    int fg = *flag;

    float v = (tid < t) ? attWf[(size_t)t * T_ + tid] : 0.f;
    red[tid] = v; __syncthreads();
    for (int s = 128; s > 0; s >>= 1) { if (tid < s) red[tid] += red[tid + s]; __syncthreads(); }
    float coef = (t == 0) ? 1.f : red[0];
    __syncthreads();
    red[tid] = outWf[tid] + outWf[tid + 256]; __syncthreads();
    for (int s = 128; s > 0; s >>= 1) { if (tid < s) red[tid] += red[tid + s]; __syncthreads(); }
    float sumW = red[0];

    float base = ((t == 0) ? 0.f : attbf[t]) * sumW + outbf[0];

    if (tid < B_) {
        float s = sigmoidf_(coef * dot[(size_t)tid * T_ + t] + base);
        size_t idx = (size_t)tid * T_ + t;
        if (fg) ((float*)out)[idx] = s;
        else    ((u16*)out)[idx] = f2bf(s);
    }
}

// ---------------------------------------------------------------------------
extern "C" void kernel_launch(void* const* d_in, const int* in_sizes, int n_in,
                              void* d_out, int out_size, void* d_ws, size_t ws_size,
                              hipStream_t stream) {
    const void* x    = d_in[0];
    const void* kin  = d_in[1];
    const void* krec = d_in[2];
    const void* bias = d_in[3];
    const void* attW = d_in[4];
    const void* attb = d_in[5];
    const void* outW = d_in[6];
    const void* outb = d_in[7];

    if (ws_size < (size_t)WS_NEED) return;

    char* ws = (char*)d_ws;
    int*   flag  = (int*)(ws + WS_FLAG);
    u16*   xb    = (u16*)(ws + WS_XB);
    u16*   Wp    = (u16*)(ws + WS_WP);
    u16*   h2    = (u16*)(ws + WS_H2);
    float* dot   = (float*)(ws + WS_DOT);
    float* biasf = (float*)(ws + WS_BIASF);
    float* attWf = (float*)(ws + WS_ATTWF);
    float* attbf = (float*)(ws + WS_ATTBF);
    float* outWf = (float*)(ws + WS_OUTWF);
    float* outbf = (float*)(ws + WS_OUTBF);

    detect<<<1, 256, 0, stream>>>((const unsigned int*)kin, flag);
    convert<<<4556, 256, 0, stream>>>(x, bias, attW, attb, outW, outb, flag,
                                      xb, biasf, attWf, attbf, outWf, outbf, dot,
                                      (unsigned int*)h2);
    pack_w<<<576, 256, 0, stream>>>(kin, krec, flag, Wp);
    lstm_persist<<<64, 512, 0, stream>>>(xb, biasf, outWf, Wp, h2, dot);
    finale<<<256, 256, 0, stream>>>(attWf, attbf, outWf, outbf, dot, flag, d_out);
}